// Round 12
// baseline (803.142 us; speedup 1.0000x reference)
//
#include <hip/hip_runtime.h>
#include <math.h>
#include <stdint.h>

#define N_Q 32768
#define K_C 8192
#define D_DIM 512
#define NSTEP 16        // K=512 / BK=32
#define KT 64           // k-tiles of 128 codes

typedef __attribute__((ext_vector_type(8))) short bf16x8;
typedef __attribute__((ext_vector_type(4))) float f32x4;
typedef unsigned long long u64;

typedef const __attribute__((address_space(1))) void gv_t;
typedef __attribute__((address_space(3))) void lv_t;

static __device__ __forceinline__ void gl16(const void* g, void* l) {
    __builtin_amdgcn_global_load_lds((gv_t*)g, (lv_t*)l, 16, 0, 0);
}

static __device__ __forceinline__ unsigned short f2bf(float f) {
    unsigned u = __float_as_uint(f);
    unsigned r = u + 0x7fffu + ((u >> 16) & 1u);
    return (unsigned short)(r >> 16);
}
static __device__ __forceinline__ float bf2f(unsigned short h) {
    return __uint_as_float(((unsigned)h) << 16);
}
// monotone float->uint map (order-preserving incl. negatives)
static __device__ __forceinline__ unsigned fmap(float f) {
    unsigned u = __float_as_uint(f);
    return (u & 0x80000000u) ? ~u : (u | 0x80000000u);
}
static __device__ __forceinline__ float funmap(unsigned m) {
    return __uint_as_float((m & 0x80000000u) ? (m & 0x7fffffffu) : ~m);
}
static __device__ __forceinline__ u64 u64min(u64 a, u64 b) { return a < b ? a : b; }

// ---------------- kernel 1: normalize emb -> wh bf16, wnorm, wnorm2;
// deterministic global max of rho_w via atomicMax on monotone-uint (commutative
// + idempotent -> order-independent). rwmax_u pre-zeroed by hipMemsetAsync.
__global__ void k_normw(const float* __restrict__ w, unsigned short* __restrict__ wh,
                        float* __restrict__ wnorm, float* __restrict__ wnorm2,
                        unsigned* __restrict__ rwmax_u) {
    __shared__ float red[4];
    __shared__ float s_n;
    int k = blockIdx.x;
    int t = threadIdx.x;
    int lane = t & 63, wid = t >> 6;
    float v0 = w[(size_t)k * D_DIM + t];
    float v1 = w[(size_t)k * D_DIM + t + 256];
    float ss = fmaf(v0, v0, v1 * v1);
    for (int off = 32; off; off >>= 1) ss += __shfl_down(ss, off, 64);
    if (lane == 0) red[wid] = ss;
    __syncthreads();
    if (t == 0) s_n = fmaxf(sqrtf(red[0] + red[1] + red[2] + red[3]), 1e-12f);
    __syncthreads();
    float n = s_n;
    float a0 = v0 / n, a1 = v1 / n;
    unsigned short h0 = f2bf(a0), h1 = f2bf(a1);
    wh[(size_t)k * D_DIM + t] = h0;
    wh[(size_t)k * D_DIM + t + 256] = h1;
    float r0 = a0 - bf2f(h0), r1 = a1 - bf2f(h1);
    float s2 = fmaf(a0, a0, a1 * a1);
    float sr = fmaf(r0, r0, r1 * r1);
    for (int off = 32; off; off >>= 1) s2 += __shfl_down(s2, off, 64);
    for (int off = 32; off; off >>= 1) sr += __shfl_down(sr, off, 64);
    __syncthreads();
    if (lane == 0) red[wid] = s2;
    __syncthreads();
    float tot2 = red[0] + red[1] + red[2] + red[3];
    __syncthreads();
    if (lane == 0) red[wid] = sr;
    __syncthreads();
    if (t == 0) {
        wnorm[k] = n;
        wnorm2[k] = tot2;
        float rho = sqrtf(red[0] + red[1] + red[2] + red[3]);
        atomicMax(rwmax_u, fmap(rho));   // rho >= 0 -> monotone map
    }
}

// ---------------- kernel 2: xnorm, xh bf16, weps[n]
__global__ void k_normx(const float* __restrict__ x, const unsigned* __restrict__ rwmax_u,
                        float* __restrict__ xnorm, unsigned short* __restrict__ xh,
                        float* __restrict__ weps) {
    int wid = threadIdx.x >> 6, lane = threadIdx.x & 63;
    int n = blockIdx.x * 4 + wid;
    const float* xr = x + (size_t)n * D_DIM;
    float v[8];
    float ss = 0.f;
    #pragma unroll
    for (int i = 0; i < 8; ++i) {
        v[i] = xr[lane + i * 64];
        ss = fmaf(v[i], v[i], ss);
    }
    for (int off = 32; off; off >>= 1) ss += __shfl_down(ss, off, 64);
    ss = __shfl(ss, 0, 64);
    float nrm = fmaxf(sqrtf(ss), 1e-12f);
    float sr = 0.f;
    #pragma unroll
    for (int i = 0; i < 8; ++i) {
        float a = v[i] / nrm;
        unsigned short h = f2bf(a);
        xh[(size_t)n * D_DIM + lane + i * 64] = h;
        float r = a - bf2f(h);
        sr = fmaf(r, r, sr);
    }
    for (int off = 32; off; off >>= 1) sr += __shfl_down(sr, off, 64);
    if (lane == 0) {
        xnorm[n] = nrm;
        float rho = sqrtf(sr);
        float rwm = funmap(rwmax_u[0]);
        // W = 2*eps, eps = 2*(rho_x + (1+rho_x)*rho_w_max) + fp32-accum slack
        weps[n] = 2.f * (2.f * (rho + (1.f + rho) * rwm) + 1.5e-4f);
    }
}

// ---------------- kernel 3: hh-only MFMA score + per-128-tile argmin + window count
// Round-11 kernel verbatim (proven 486us, bitwise-fixed dist_hh) EXCEPT the
// epilogue store layout: pmin/cnt now [n][64] (transposed) so k_final's
// per-wave candidate read is one contiguous 512B segment.
// Block 128 rows x 256 codes, 8 waves (2M x 4N), per-wave 64x64, BK=32.
// LDS double buffer 2 x 24KB = 48KB. __syncthreads-only schedule.
// Chunk swizzle phys = r*4 + (g ^ ((r>>1)&3)) (0-conflict, measured r2-r11).
__global__ __launch_bounds__(512, 4) void k_score(
    const unsigned short* __restrict__ xh, const unsigned short* __restrict__ wh,
    const float* __restrict__ wnorm2, const float* __restrict__ weps,
    u64* __restrict__ pmin_part, unsigned char* __restrict__ cnt_part)
{
    __shared__ __align__(16) char lds[49152];
    int tid = threadIdx.x;                 // 512
    int lane = tid & 63, wid = tid >> 6;   // 8 waves
    int wm = wid >> 2, wn = wid & 3;       // 2 x 4
    int ktp = blockIdx.x;                  // 0..31 (pair of 128-code tiles)
    int k0 = ktp * 256;
    int n0 = blockIdx.y * 128;
    int c15 = lane & 15, g = lane >> 4;

    int aoff[4], boff[4];
    #pragma unroll
    for (int f = 0; f < 4; ++f) {
        int ar = wm * 64 + f * 16 + c15;                  // 0..127
        aoff[f] = (ar * 4 + (g ^ ((ar >> 1) & 3))) * 16;
        int br = wn * 64 + f * 16 + c15;                  // 0..255
        boff[f] = (br * 4 + (g ^ ((br >> 1) & 3))) * 16;
    }

    // staging sources: A chunk p=tid (rows 0..127); B chunks p=tid and p=tid+512
    int ra = tid >> 2, ga = (tid & 3) ^ ((tid >> 3) & 3);
    size_t aA  = (size_t)(n0 + ra) * D_DIM + ga * 8;
    size_t aB0 = (size_t)(k0 + ra) * D_DIM + ga * 8;
    size_t aB1 = (size_t)(k0 + 128 + ra) * D_DIM + ga * 8;

    f32x4 acc[4][4];
    #pragma unroll
    for (int i = 0; i < 4; ++i)
        #pragma unroll
        for (int j = 0; j < 4; ++j) acc[i][j] = (f32x4){0.f, 0.f, 0.f, 0.f};

    // prologue: stage step 0 into buf0 (A at 0, B at 8192..24575)
    gl16(xh + aA, lds + tid * 16);
    gl16(wh + aB0, lds + 8192 + tid * 16);
    gl16(wh + aB1, lds + 16384 + tid * 16);
    __syncthreads();

    for (int t = 0; t < NSTEP; ++t) {
        if (t < NSTEP - 1) {
            int du = (t + 1) * 32;
            char* nb = lds + (((t + 1) & 1) ? 24576 : 0);
            gl16(xh + aA + du, nb + tid * 16);
            gl16(wh + aB0 + du, nb + 8192 + tid * 16);
            gl16(wh + aB1 + du, nb + 16384 + tid * 16);
        }
        const char* cb = lds + ((t & 1) ? 24576 : 0);
        bf16x8 ah[4], bh[4];
        #pragma unroll
        for (int f = 0; f < 4; ++f) {
            ah[f] = *(const bf16x8*)(cb + aoff[f]);
            bh[f] = *(const bf16x8*)(cb + 8192 + boff[f]);
        }
        #pragma unroll
        for (int i = 0; i < 4; ++i)
            #pragma unroll
            for (int j = 0; j < 4; ++j)
                acc[i][j] = __builtin_amdgcn_mfma_f32_16x16x32_bf16(ah[i], bh[j], acc[i][j], 0, 0, 0);
        __syncthreads();
    }

    // ---- epilogue: two 128-code tiles per block (half = wn>>1)
    float w2[4];
    #pragma unroll
    for (int j = 0; j < 4; ++j) w2[j] = wnorm2[k0 + wn * 64 + j * 16 + c15];

    u64* scr = (u64*)lds;                         // [128 rows][4 wn] = 4KB
    float* tminS = (float*)(lds + 4096);          // [128][2] = 1KB
    float* wepsS = tminS + 256;                   // [128]    = 512B
    int* cntS = (int*)(wepsS + 128);              // [128][2] = 1KB

    #pragma unroll
    for (int m = 0; m < 4; ++m) {
        #pragma unroll
        for (int reg = 0; reg < 4; ++reg) {
            float bv = INFINITY;
            int bk = 0x7fffffff;
            #pragma unroll
            for (int j = 0; j < 4; ++j) {
                float v = fmaf(-2.f, acc[m][j][reg], w2[j]);
                int kk = k0 + wn * 64 + j * 16 + c15;
                if (v < bv || (v == bv && kk < bk)) { bv = v; bk = kk; }
            }
            for (int off = 8; off; off >>= 1) {
                float v2 = __shfl_xor(bv, off, 16);
                int k2 = __shfl_xor(bk, off, 16);
                if (v2 < bv || (v2 == bv && k2 < bk)) { bv = v2; bk = k2; }
            }
            if (c15 == 0) {
                int row = wm * 64 + m * 16 + g * 4 + reg;   // 0..127
                scr[row * 4 + wn] = ((u64)fmap(bv) << 32) | (unsigned)bk;
            }
        }
    }
    __syncthreads();
    if (tid < 256) {
        int row = tid >> 1, half = tid & 1;
        u64 a = scr[row * 4 + half * 2], b = scr[row * 4 + half * 2 + 1];
        u64 mn = (b < a) ? b : a;
        pmin_part[(size_t)(n0 + row) * KT + (ktp * 2 + half)] = mn;   // [n][64]
        tminS[row * 2 + half] = funmap((unsigned)(mn >> 32));
        cntS[row * 2 + half] = 0;
    }
    if (tid >= 256 && tid < 384) wepsS[tid - 256] = weps[n0 + tid - 256];
    __syncthreads();
    // count codes with dist <= tile_min + W (same fmaf -> bitwise identical)
    {
        int half = wn >> 1;
        #pragma unroll
        for (int m = 0; m < 4; ++m) {
            #pragma unroll
            for (int reg = 0; reg < 4; ++reg) {
                int row = wm * 64 + m * 16 + g * 4 + reg;
                float thr = tminS[row * 2 + half] + wepsS[row];
                int c = 0;
                #pragma unroll
                for (int j = 0; j < 4; ++j) {
                    float v = fmaf(-2.f, acc[m][j][reg], w2[j]);
                    c += (v <= thr) ? 1 : 0;
                }
                for (int off = 8; off; off >>= 1) c += __shfl_xor(c, off, 16);
                if (c15 == 0) atomicAdd(&cntS[row * 2 + half], c);
            }
        }
    }
    __syncthreads();
    if (tid < 256) {
        int row = tid >> 1, half = tid & 1;
        int c = cntS[tid];
        cnt_part[(size_t)(n0 + row) * KT + (ktp * 2 + half)] =        // [n][64]
            (unsigned char)(c > 255 ? 255 : c);
    }
}

// ---------------- kernel 4: refine (exact fp32 argmin over pruned candidates)
// + gather + loss partial, fused. Transposed pmin/cnt: per-wave reads are one
// contiguous 512B (u64) + 64B (u8) segment.
__global__ void k_final(const float* __restrict__ x, const float* __restrict__ emb,
                        const float* __restrict__ xnorm, const float* __restrict__ wnorm,
                        const float* __restrict__ wnorm2, const float* __restrict__ weps,
                        const u64* __restrict__ pmin_part,
                        const unsigned char* __restrict__ cnt_part,
                        float* __restrict__ qout, float* __restrict__ idxf,
                        float* __restrict__ partials) {
    __shared__ float red[4];
    int t = threadIdx.x, lane = t & 63, wid = t >> 6;
    int n = blockIdx.x * 4 + wid;

    u64 pm = pmin_part[(size_t)n * KT + lane];
    int cnt = cnt_part[(size_t)n * KT + lane];
    u64 mn = pm;
    for (int off = 32; off; off >>= 1) mn = u64min(mn, __shfl_xor(mn, off, 64));
    float thr = funmap((unsigned)(mn >> 32)) + weps[n];

    float xn = xnorm[n];
    const float4* xp = (const float4*)(x + (size_t)n * D_DIM + lane * 8);
    float4 xa = xp[0], xb = xp[1];
    xa.x /= xn; xa.y /= xn; xa.z /= xn; xa.w /= xn;
    xb.x /= xn; xb.y /= xn; xb.z /= xn; xb.w /= xn;

    u64 best = 0xFFFFFFFFFFFFFFFFull;
    u64 cand = __ballot(funmap((unsigned)(pm >> 32)) <= thr);
    while (cand) {
        int tt = __builtin_ctzll(cand);
        cand &= cand - 1;
        u64 pmt = __shfl(pm, tt);
        int ct = __shfl(cnt, tt);
        int kbeg, kend;
        if (ct == 1) { kbeg = (int)(unsigned)(pmt & 0xffffffffull); kend = kbeg + 1; }
        else { kbeg = tt * 128; kend = kbeg + 128; }
        for (int k = kbeg; k < kend; ++k) {
            const float4* ep = (const float4*)(emb + (size_t)k * D_DIM + lane * 8);
            float4 e0 = ep[0], e1 = ep[1];
            float dt = xa.x * e0.x + xa.y * e0.y + xa.z * e0.z + xa.w * e0.w
                     + xb.x * e1.x + xb.y * e1.y + xb.z * e1.z + xb.w * e1.w;
            for (int off = 32; off; off >>= 1) dt += __shfl_xor(dt, off, 64);
            float dist = fmaf(-2.f, dt / wnorm[k], wnorm2[k]);
            u64 pk = ((u64)fmap(dist) << 32) | (unsigned)k;
            if (pk < best) best = pk;
        }
    }

    int kk = (int)(unsigned)(best & 0xffffffffull);
    float nn = wnorm[kk];
    const float* er = emb + (size_t)kk * D_DIM + lane * 8;
    float4 e0 = *(const float4*)er;
    float4 e1 = *(const float4*)(er + 4);
    float4 q0, q1;
    q0.x = e0.x / nn; q0.y = e0.y / nn; q0.z = e0.z / nn; q0.w = e0.w / nn;
    q1.x = e1.x / nn; q1.y = e1.y / nn; q1.z = e1.z / nn; q1.w = e1.w / nn;

    float d0 = xa.x - q0.x, d1 = xa.y - q0.y, d2 = xa.z - q0.z, d3 = xa.w - q0.w;
    float d4 = xb.x - q1.x, d5 = xb.y - q1.y, d6 = xb.z - q1.z, d7 = xb.w - q1.w;
    float ds = d0 * d0 + d1 * d1 + d2 * d2 + d3 * d3
             + d4 * d4 + d5 * d5 + d6 * d6 + d7 * d7;

    float* qo = qout + (size_t)n * D_DIM + lane * 8;
    *(float4*)qo = q0;
    *(float4*)(qo + 4) = q1;
    if (lane == 0) idxf[n] = (float)kk;

    for (int off = 32; off; off >>= 1) ds += __shfl_down(ds, off, 64);
    if (lane == 0) red[wid] = ds;
    __syncthreads();
    if (t == 0) partials[blockIdx.x] = red[0] + red[1] + red[2] + red[3];
}

// ---------------- kernel 5: deterministic final loss reduction
__global__ void k_loss(const float* __restrict__ partials, float* __restrict__ out_loss) {
    __shared__ float red[4];
    int t = threadIdx.x, lane = t & 63, wid = t >> 6;
    float s = 0.f;
    for (int i = t; i < 8192; i += 256) s += partials[i];
    for (int off = 32; off; off >>= 1) s += __shfl_down(s, off, 64);
    if (lane == 0) red[wid] = s;
    __syncthreads();
    if (t == 0)
        out_loss[0] = (red[0] + red[1] + red[2] + red[3]) * (1.25f / ((float)N_Q * (float)D_DIM));
}

extern "C" void kernel_launch(void* const* d_in, const int* in_sizes, int n_in,
                              void* d_out, int out_size, void* d_ws, size_t ws_size,
                              hipStream_t stream) {
    (void)in_sizes; (void)n_in; (void)out_size; (void)ws_size;
    const float* x = (const float*)d_in[0];
    const float* w = (const float*)d_in[1];

    float* out = (float*)d_out;
    float* qout = out;                                  // N*D f32
    float* loss = out + (size_t)N_Q * D_DIM;            // 1
    float* idxf = loss + 1;                             // N

    // xh bf16 scratch lives in the qout region (first N*D shorts),
    // consumed by k_score, then qout overwritten by k_final.
    unsigned short* xh = (unsigned short*)qout;

    char* ws = (char*)d_ws;
    unsigned short* wh = (unsigned short*)ws;                       // 8 MB
    float* wnorm2 = (float*)(wh + (size_t)K_C * D_DIM);             // 32 KB
    float* wnorm = wnorm2 + K_C;                                    // 32 KB
    unsigned* rwmax_u = (unsigned*)(wnorm + K_C);                   // 4 B (+pad 64)
    float* xnorm = (float*)(rwmax_u + 64);                          // 128 KB
    float* weps = xnorm + N_Q;                                      // 128 KB
    u64* pmin_part = (u64*)(weps + N_Q);                            // N*64 u64 = 16 MB
    unsigned char* cnt_part = (unsigned char*)(pmin_part + (size_t)N_Q * KT); // 2 MB
    float* partials = (float*)(cnt_part + (size_t)N_Q * KT);        // 32 KB

    hipMemsetAsync(rwmax_u, 0, sizeof(unsigned), stream);
    k_normw<<<K_C, 256, 0, stream>>>(w, wh, wnorm, wnorm2, rwmax_u);
    k_normx<<<N_Q / 4, 256, 0, stream>>>(x, rwmax_u, xnorm, xh, weps);
    dim3 grid(KT / 2, N_Q / 128);
    k_score<<<grid, 512, 0, stream>>>(xh, wh, wnorm2, weps, pmin_part, cnt_part);
    k_final<<<N_Q / 4, 256, 0, stream>>>(x, w, xnorm, wnorm, wnorm2, weps,
                                         pmin_part, cnt_part, qout, idxf, partials);
    k_loss<<<1, 256, 0, stream>>>(partials, loss);
}

// Round 13
// 624.443 us; speedup vs baseline: 1.2862x; 1.2862x over previous
//
#include <hip/hip_runtime.h>
#include <math.h>
#include <stdint.h>

#define N_Q 32768
#define K_C 8192
#define D_DIM 512
#define NSTEP 16        // K=512 / BK=32
#define KT 64           // k-tiles of 128 codes

typedef __attribute__((ext_vector_type(8))) short bf16x8;
typedef __attribute__((ext_vector_type(4))) float f32x4;
typedef unsigned long long u64;

typedef const __attribute__((address_space(1))) void gv_t;
typedef __attribute__((address_space(3))) void lv_t;

static __device__ __forceinline__ void gl16(const void* g, void* l) {
    __builtin_amdgcn_global_load_lds((gv_t*)g, (lv_t*)l, 16, 0, 0);
}

static __device__ __forceinline__ unsigned short f2bf(float f) {
    unsigned u = __float_as_uint(f);
    unsigned r = u + 0x7fffu + ((u >> 16) & 1u);
    return (unsigned short)(r >> 16);
}
static __device__ __forceinline__ float bf2f(unsigned short h) {
    return __uint_as_float(((unsigned)h) << 16);
}
// monotone float->uint map (order-preserving incl. negatives)
static __device__ __forceinline__ unsigned fmap(float f) {
    unsigned u = __float_as_uint(f);
    return (u & 0x80000000u) ? ~u : (u | 0x80000000u);
}
static __device__ __forceinline__ float funmap(unsigned m) {
    return __uint_as_float((m & 0x80000000u) ? (m & 0x7fffffffu) : ~m);
}
static __device__ __forceinline__ u64 u64min(u64 a, u64 b) { return a < b ? a : b; }

// ---------------- kernel 1: normalize emb -> wh bf16, wnorm, wnorm2, rho_w
__global__ void k_normw(const float* __restrict__ w, unsigned short* __restrict__ wh,
                        float* __restrict__ wnorm, float* __restrict__ wnorm2,
                        float* __restrict__ rho_w) {
    __shared__ float red[4];
    __shared__ float s_n;
    int k = blockIdx.x;
    int t = threadIdx.x;
    int lane = t & 63, wid = t >> 6;
    float v0 = w[(size_t)k * D_DIM + t];
    float v1 = w[(size_t)k * D_DIM + t + 256];
    float ss = fmaf(v0, v0, v1 * v1);
    for (int off = 32; off; off >>= 1) ss += __shfl_down(ss, off, 64);
    if (lane == 0) red[wid] = ss;
    __syncthreads();
    if (t == 0) s_n = fmaxf(sqrtf(red[0] + red[1] + red[2] + red[3]), 1e-12f);
    __syncthreads();
    float n = s_n;
    float a0 = v0 / n, a1 = v1 / n;
    unsigned short h0 = f2bf(a0), h1 = f2bf(a1);
    wh[(size_t)k * D_DIM + t] = h0;
    wh[(size_t)k * D_DIM + t + 256] = h1;
    float r0 = a0 - bf2f(h0), r1 = a1 - bf2f(h1);
    float s2 = fmaf(a0, a0, a1 * a1);
    float sr = fmaf(r0, r0, r1 * r1);
    for (int off = 32; off; off >>= 1) s2 += __shfl_down(s2, off, 64);
    for (int off = 32; off; off >>= 1) sr += __shfl_down(sr, off, 64);
    __syncthreads();
    if (lane == 0) red[wid] = s2;
    __syncthreads();
    float tot2 = red[0] + red[1] + red[2] + red[3];
    __syncthreads();
    if (lane == 0) red[wid] = sr;
    __syncthreads();
    if (t == 0) {
        wnorm[k] = n;
        wnorm2[k] = tot2;
        rho_w[k] = sqrtf(red[0] + red[1] + red[2] + red[3]);
    }
}

// ---------------- kernel 2: rho_w_max (deterministic)
__global__ void k_wmax(const float* __restrict__ rho_w, float* __restrict__ rwmax) {
    __shared__ float red[4];
    int t = threadIdx.x, lane = t & 63, wid = t >> 6;
    float m = 0.f;
    for (int i = t; i < K_C; i += 256) m = fmaxf(m, rho_w[i]);
    for (int off = 32; off; off >>= 1) m = fmaxf(m, __shfl_down(m, off, 64));
    if (lane == 0) red[wid] = m;
    __syncthreads();
    if (t == 0) rwmax[0] = fmaxf(fmaxf(red[0], red[1]), fmaxf(red[2], red[3]));
}

// ---------------- kernel 3: xnorm, xh bf16, weps[n]
__global__ void k_normx(const float* __restrict__ x, const float* __restrict__ rwmax,
                        float* __restrict__ xnorm, unsigned short* __restrict__ xh,
                        float* __restrict__ weps) {
    int wid = threadIdx.x >> 6, lane = threadIdx.x & 63;
    int n = blockIdx.x * 4 + wid;
    const float* xr = x + (size_t)n * D_DIM;
    float v[8];
    float ss = 0.f;
    #pragma unroll
    for (int i = 0; i < 8; ++i) {
        v[i] = xr[lane + i * 64];
        ss = fmaf(v[i], v[i], ss);
    }
    for (int off = 32; off; off >>= 1) ss += __shfl_down(ss, off, 64);
    ss = __shfl(ss, 0, 64);
    float nrm = fmaxf(sqrtf(ss), 1e-12f);
    float sr = 0.f;
    #pragma unroll
    for (int i = 0; i < 8; ++i) {
        float a = v[i] / nrm;
        unsigned short h = f2bf(a);
        xh[(size_t)n * D_DIM + lane + i * 64] = h;
        float r = a - bf2f(h);
        sr = fmaf(r, r, sr);
    }
    for (int off = 32; off; off >>= 1) sr += __shfl_down(sr, off, 64);
    if (lane == 0) {
        xnorm[n] = nrm;
        float rho = sqrtf(sr);
        float rwm = rwmax[0];
        // W = 2*eps, eps = 2*(rho_x + (1+rho_x)*rho_w_max) + fp32-accum slack
        weps[n] = 2.f * (2.f * (rho + (1.f + rho) * rwm) + 1.5e-4f);
    }
}

// ---------------- kernel 4: hh-only MFMA score + per-128-tile argmin + window count
// Round-11 kernel verbatim (proven 486us / 721us total, passed).
// Block 128 rows x 256 codes, 8 waves (2M x 4N), per-wave 64x64, BK=32.
// LDS double buffer 2 x 24KB = 48KB. __syncthreads-only schedule.
// pmin/cnt layout [ktile][n] (producer write-coalesced; r12's [n][64] transpose
// tripled WRITE_SIZE via cross-block false sharing and regressed).
__global__ __launch_bounds__(512, 4) void k_score(
    const unsigned short* __restrict__ xh, const unsigned short* __restrict__ wh,
    const float* __restrict__ wnorm2, const float* __restrict__ weps,
    u64* __restrict__ pmin_part, unsigned char* __restrict__ cnt_part)
{
    __shared__ __align__(16) char lds[49152];
    int tid = threadIdx.x;                 // 512
    int lane = tid & 63, wid = tid >> 6;   // 8 waves
    int wm = wid >> 2, wn = wid & 3;       // 2 x 4
    int ktp = blockIdx.x;                  // 0..31 (pair of 128-code tiles)
    int k0 = ktp * 256;
    int n0 = blockIdx.y * 128;
    int c15 = lane & 15, g = lane >> 4;

    int aoff[4], boff[4];
    #pragma unroll
    for (int f = 0; f < 4; ++f) {
        int ar = wm * 64 + f * 16 + c15;                  // 0..127
        aoff[f] = (ar * 4 + (g ^ ((ar >> 1) & 3))) * 16;
        int br = wn * 64 + f * 16 + c15;                  // 0..255
        boff[f] = (br * 4 + (g ^ ((br >> 1) & 3))) * 16;
    }

    // staging sources: A chunk p=tid (rows 0..127); B chunks p=tid and p=tid+512
    int ra = tid >> 2, ga = (tid & 3) ^ ((tid >> 3) & 3);
    size_t aA  = (size_t)(n0 + ra) * D_DIM + ga * 8;
    size_t aB0 = (size_t)(k0 + ra) * D_DIM + ga * 8;
    size_t aB1 = (size_t)(k0 + 128 + ra) * D_DIM + ga * 8;

    f32x4 acc[4][4];
    #pragma unroll
    for (int i = 0; i < 4; ++i)
        #pragma unroll
        for (int j = 0; j < 4; ++j) acc[i][j] = (f32x4){0.f, 0.f, 0.f, 0.f};

    // prologue: stage step 0 into buf0 (A at 0, B at 8192..24575)
    gl16(xh + aA, lds + tid * 16);
    gl16(wh + aB0, lds + 8192 + tid * 16);
    gl16(wh + aB1, lds + 16384 + tid * 16);
    __syncthreads();

    for (int t = 0; t < NSTEP; ++t) {
        if (t < NSTEP - 1) {
            int du = (t + 1) * 32;
            char* nb = lds + (((t + 1) & 1) ? 24576 : 0);
            gl16(xh + aA + du, nb + tid * 16);
            gl16(wh + aB0 + du, nb + 8192 + tid * 16);
            gl16(wh + aB1 + du, nb + 16384 + tid * 16);
        }
        const char* cb = lds + ((t & 1) ? 24576 : 0);
        bf16x8 ah[4], bh[4];
        #pragma unroll
        for (int f = 0; f < 4; ++f) {
            ah[f] = *(const bf16x8*)(cb + aoff[f]);
            bh[f] = *(const bf16x8*)(cb + 8192 + boff[f]);
        }
        #pragma unroll
        for (int i = 0; i < 4; ++i)
            #pragma unroll
            for (int j = 0; j < 4; ++j)
                acc[i][j] = __builtin_amdgcn_mfma_f32_16x16x32_bf16(ah[i], bh[j], acc[i][j], 0, 0, 0);
        __syncthreads();
    }

    // ---- epilogue: two 128-code tiles per block (half = wn>>1)
    float w2[4];
    #pragma unroll
    for (int j = 0; j < 4; ++j) w2[j] = wnorm2[k0 + wn * 64 + j * 16 + c15];

    u64* scr = (u64*)lds;                         // [128 rows][4 wn] = 4KB
    float* tminS = (float*)(lds + 4096);          // [128][2] = 1KB
    float* wepsS = tminS + 256;                   // [128]    = 512B
    int* cntS = (int*)(wepsS + 128);              // [128][2] = 1KB

    #pragma unroll
    for (int m = 0; m < 4; ++m) {
        #pragma unroll
        for (int reg = 0; reg < 4; ++reg) {
            float bv = INFINITY;
            int bk = 0x7fffffff;
            #pragma unroll
            for (int j = 0; j < 4; ++j) {
                float v = fmaf(-2.f, acc[m][j][reg], w2[j]);
                int kk = k0 + wn * 64 + j * 16 + c15;
                if (v < bv || (v == bv && kk < bk)) { bv = v; bk = kk; }
            }
            for (int off = 8; off; off >>= 1) {
                float v2 = __shfl_xor(bv, off, 16);
                int k2 = __shfl_xor(bk, off, 16);
                if (v2 < bv || (v2 == bv && k2 < bk)) { bv = v2; bk = k2; }
            }
            if (c15 == 0) {
                int row = wm * 64 + m * 16 + g * 4 + reg;   // 0..127
                scr[row * 4 + wn] = ((u64)fmap(bv) << 32) | (unsigned)bk;
            }
        }
    }
    __syncthreads();
    if (tid < 256) {
        int row = tid >> 1, half = tid & 1;
        u64 a = scr[row * 4 + half * 2], b = scr[row * 4 + half * 2 + 1];
        u64 mn = (b < a) ? b : a;
        pmin_part[(size_t)(ktp * 2 + half) * N_Q + n0 + row] = mn;
        tminS[row * 2 + half] = funmap((unsigned)(mn >> 32));
        cntS[row * 2 + half] = 0;
    }
    if (tid >= 256 && tid < 384) wepsS[tid - 256] = weps[n0 + tid - 256];
    __syncthreads();
    // count codes with dist <= tile_min + W (same fmaf -> bitwise identical)
    {
        int half = wn >> 1;
        #pragma unroll
        for (int m = 0; m < 4; ++m) {
            #pragma unroll
            for (int reg = 0; reg < 4; ++reg) {
                int row = wm * 64 + m * 16 + g * 4 + reg;
                float thr = tminS[row * 2 + half] + wepsS[row];
                int c = 0;
                #pragma unroll
                for (int j = 0; j < 4; ++j) {
                    float v = fmaf(-2.f, acc[m][j][reg], w2[j]);
                    c += (v <= thr) ? 1 : 0;
                }
                for (int off = 8; off; off >>= 1) c += __shfl_xor(c, off, 16);
                if (c15 == 0) atomicAdd(&cntS[row * 2 + half], c);
            }
        }
    }
    __syncthreads();
    if (tid < 256) {
        int row = tid >> 1, half = tid & 1;
        int c = cntS[tid];
        cnt_part[(size_t)(ktp * 2 + half) * N_Q + n0 + row] =
            (unsigned char)(c > 255 ? 255 : c);
    }
}

// ---------------- kernel 5: refine + gather + loss partial, fused.
// Candidate set and comparator identical to rounds 6-11. Rescan path (cnt>=2)
// is now LANE-PARALLEL: x-row staged in LDS (broadcast reads), each lane owns
// one code and computes the full 512-d dot serially; per-lane packed bests
// merged by a deterministic wave-wide u64min at the end.
__global__ void k_final(const float* __restrict__ x, const float* __restrict__ emb,
                        const float* __restrict__ xnorm, const float* __restrict__ wnorm,
                        const float* __restrict__ wnorm2, const float* __restrict__ weps,
                        const u64* __restrict__ pmin_part,
                        const unsigned char* __restrict__ cnt_part,
                        float* __restrict__ qout, float* __restrict__ idxf,
                        float* __restrict__ partials) {
    __shared__ float red[4];
    __shared__ float xs[4][D_DIM];        // 8KB: normalized x row per wave
    int t = threadIdx.x, lane = t & 63, wid = t >> 6;
    int n = blockIdx.x * 4 + wid;

    u64 pm = pmin_part[(size_t)lane * N_Q + n];
    int cnt = cnt_part[(size_t)lane * N_Q + n];
    u64 mn = pm;
    for (int off = 32; off; off >>= 1) mn = u64min(mn, __shfl_xor(mn, off, 64));
    float thr = funmap((unsigned)(mn >> 32)) + weps[n];

    float xn = xnorm[n];
    const float4* xp = (const float4*)(x + (size_t)n * D_DIM + lane * 8);
    float4 xa = xp[0], xb = xp[1];
    xa.x /= xn; xa.y /= xn; xa.z /= xn; xa.w /= xn;
    xb.x /= xn; xb.y /= xn; xb.z /= xn; xb.w /= xn;
    // stage this wave's normalized row for lane-parallel rescans
    *(float4*)&xs[wid][lane * 8] = xa;
    *(float4*)&xs[wid][lane * 8 + 4] = xb;

    u64 best = 0xFFFFFFFFFFFFFFFFull;
    u64 cand = __ballot(funmap((unsigned)(pm >> 32)) <= thr);
    while (cand) {
        int tt = __builtin_ctzll(cand);
        cand &= cand - 1;
        u64 pmt = __shfl(pm, tt);
        int ct = __shfl(cnt, tt);
        if (ct == 1) {
            // single candidate: wave-parallel dot (all lanes same result)
            int k = (int)(unsigned)(pmt & 0xffffffffull);
            const float4* ep = (const float4*)(emb + (size_t)k * D_DIM + lane * 8);
            float4 e0 = ep[0], e1 = ep[1];
            float dt = xa.x * e0.x + xa.y * e0.y + xa.z * e0.z + xa.w * e0.w
                     + xb.x * e1.x + xb.y * e1.y + xb.z * e1.z + xb.w * e1.w;
            for (int off = 32; off; off >>= 1) dt += __shfl_xor(dt, off, 64);
            float dist = fmaf(-2.f, dt / wnorm[k], wnorm2[k]);
            u64 pk = ((u64)fmap(dist) << 32) | (unsigned)k;
            best = u64min(best, pk);
        } else {
            // rescan 128 codes lane-parallel: lane owns codes tt*128+lane(+64)
            #pragma unroll
            for (int pass = 0; pass < 2; ++pass) {
                int k = tt * 128 + pass * 64 + lane;
                const float4* ep = (const float4*)(emb + (size_t)k * D_DIM);
                float dt = 0.f;
                #pragma unroll 8
                for (int i = 0; i < D_DIM / 4; ++i) {
                    float4 e = ep[i];
                    dt = fmaf(xs[wid][i * 4 + 0], e.x, dt);
                    dt = fmaf(xs[wid][i * 4 + 1], e.y, dt);
                    dt = fmaf(xs[wid][i * 4 + 2], e.z, dt);
                    dt = fmaf(xs[wid][i * 4 + 3], e.w, dt);
                }
                float dist = fmaf(-2.f, dt / wnorm[k], wnorm2[k]);
                u64 pk = ((u64)fmap(dist) << 32) | (unsigned)k;
                best = u64min(best, pk);
            }
        }
    }
    // merge per-lane bests (deterministic; no-op for ct==1-only rows)
    for (int off = 32; off; off >>= 1) best = u64min(best, __shfl_xor(best, off, 64));

    int kk = (int)(unsigned)(best & 0xffffffffull);
    float nn = wnorm[kk];
    const float* er = emb + (size_t)kk * D_DIM + lane * 8;
    float4 e0 = *(const float4*)er;
    float4 e1 = *(const float4*)(er + 4);
    float4 q0, q1;
    q0.x = e0.x / nn; q0.y = e0.y / nn; q0.z = e0.z / nn; q0.w = e0.w / nn;
    q1.x = e1.x / nn; q1.y = e1.y / nn; q1.z = e1.z / nn; q1.w = e1.w / nn;

    float d0 = xa.x - q0.x, d1 = xa.y - q0.y, d2 = xa.z - q0.z, d3 = xa.w - q0.w;
    float d4 = xb.x - q1.x, d5 = xb.y - q1.y, d6 = xb.z - q1.z, d7 = xb.w - q1.w;
    float ds = d0 * d0 + d1 * d1 + d2 * d2 + d3 * d3
             + d4 * d4 + d5 * d5 + d6 * d6 + d7 * d7;

    float* qo = qout + (size_t)n * D_DIM + lane * 8;
    *(float4*)qo = q0;
    *(float4*)(qo + 4) = q1;
    if (lane == 0) idxf[n] = (float)kk;

    for (int off = 32; off; off >>= 1) ds += __shfl_down(ds, off, 64);
    if (lane == 0) red[wid] = ds;
    __syncthreads();
    if (t == 0) partials[blockIdx.x] = red[0] + red[1] + red[2] + red[3];
}

// ---------------- kernel 6: deterministic final loss reduction
__global__ void k_loss(const float* __restrict__ partials, float* __restrict__ out_loss) {
    __shared__ float red[4];
    int t = threadIdx.x, lane = t & 63, wid = t >> 6;
    float s = 0.f;
    for (int i = t; i < 8192; i += 256) s += partials[i];
    for (int off = 32; off; off >>= 1) s += __shfl_down(s, off, 64);
    if (lane == 0) red[wid] = s;
    __syncthreads();
    if (t == 0)
        out_loss[0] = (red[0] + red[1] + red[2] + red[3]) * (1.25f / ((float)N_Q * (float)D_DIM));
}

extern "C" void kernel_launch(void* const* d_in, const int* in_sizes, int n_in,
                              void* d_out, int out_size, void* d_ws, size_t ws_size,
                              hipStream_t stream) {
    (void)in_sizes; (void)n_in; (void)out_size; (void)ws_size;
    const float* x = (const float*)d_in[0];
    const float* w = (const float*)d_in[1];

    float* out = (float*)d_out;
    float* qout = out;                                  // N*D f32
    float* loss = out + (size_t)N_Q * D_DIM;            // 1
    float* idxf = loss + 1;                             // N

    // xh bf16 scratch lives in the qout region (first N*D shorts),
    // consumed by k_score, then qout overwritten by k_final.
    unsigned short* xh = (unsigned short*)qout;

    char* ws = (char*)d_ws;
    unsigned short* wh = (unsigned short*)ws;                       // 8 MB
    float* wnorm2 = (float*)(wh + (size_t)K_C * D_DIM);             // 32 KB
    float* wnorm = wnorm2 + K_C;                                    // 32 KB
    float* rho_w = wnorm + K_C;                                     // 32 KB
    float* rwmax = rho_w + K_C;                                     // pad
    float* xnorm = rwmax + 64;                                      // 128 KB
    float* weps = xnorm + N_Q;                                      // 128 KB
    u64* pmin_part = (u64*)(weps + N_Q);                            // 16 MB
    unsigned char* cnt_part = (unsigned char*)(pmin_part + (size_t)KT * N_Q); // 2 MB
    float* partials = (float*)(cnt_part + (size_t)KT * N_Q);        // 32 KB

    k_normw<<<K_C, 256, 0, stream>>>(w, wh, wnorm, wnorm2, rho_w);
    k_wmax<<<1, 256, 0, stream>>>(rho_w, rwmax);
    k_normx<<<N_Q / 4, 256, 0, stream>>>(x, rwmax, xnorm, xh, weps);
    dim3 grid(KT / 2, N_Q / 128);
    k_score<<<grid, 512, 0, stream>>>(xh, wh, wnorm2, weps, pmin_part, cnt_part);
    k_final<<<N_Q / 4, 256, 0, stream>>>(x, w, xnorm, wnorm, wnorm2, weps,
                                         pmin_part, cnt_part, qout, idxf, partials);
    k_loss<<<1, 256, 0, stream>>>(partials, loss);
}